// Round 1
// baseline (206.817 us; speedup 1.0000x reference)
//
#include <hip/hip_runtime.h>
#include <hip/hip_bf16.h>
#include <cstdint>

#define NB 8
#define NN 384
#define OUT1OFF 196608
#define OUT2OFF 205824

typedef float f4 __attribute__((ext_vector_type(4)));
typedef short short8 __attribute__((ext_vector_type(8)));

__device__ inline unsigned short f2bf(float f) {
    unsigned int u = __float_as_uint(f);
    return (unsigned short)((u + 0x7fffu + ((u >> 16) & 1u)) >> 16);
}
__device__ inline float bfu(short s) {
    return __uint_as_float(((unsigned int)(unsigned short)s) << 16);
}
__device__ inline float siluf(float x) {
    return x * __builtin_amdgcn_rcpf(1.0f + __expf(-x));
}
__device__ inline float seluf(float x) {
    const float sc = 1.0507009873554805f, al = 1.6732632423543772f;
    return x > 0.f ? sc * x : sc * al * (__expf(x) - 1.f);
}

// ---- prep1: HiC[row,h] = be1[h] + feats[row,:]@We1[0:64,h]
//            HjC[row,h] =          feats[row,:]@We1[64:128,h]
__global__ __launch_bounds__(128) void egnn_prep1(
    const float* __restrict__ feats, const float* __restrict__ We1,
    const float* __restrict__ be1, float* __restrict__ HiC, float* __restrict__ HjC) {
    int r0 = blockIdx.x * 8;
    int t = threadIdx.x;
    __shared__ float fr[8][64];
    for (int k = t; k < 512; k += 128) fr[k >> 6][k & 63] = feats[(size_t)r0 * 64 + k];
    __syncthreads();
    float a1[8], a2[8];
#pragma unroll
    for (int r = 0; r < 8; r++) { a1[r] = be1[t]; a2[r] = 0.f; }
    for (int d = 0; d < 64; d++) {
        float w1 = We1[d * 128 + t], w2 = We1[(64 + d) * 128 + t];
#pragma unroll
        for (int r = 0; r < 8; r++) { a1[r] += fr[r][d] * w1; a2[r] += fr[r][d] * w2; }
    }
#pragma unroll
    for (int r = 0; r < 8; r++) {
        HiC[(size_t)(r0 + r) * 128 + t] = a1[r];
        HjC[(size_t)(r0 + r) * 128 + t] = a2[r];
    }
}

// ---- prep2: pack We2 / Wc1 into MFMA B-fragment order (bf16)
// B-frag layout: lane holds B[k = 8*(lane>>4)+e (+32*ks)][col = n*16 + (lane&15)]
__global__ __launch_bounds__(64) void egnn_prep2(
    const float* __restrict__ We2, const float* __restrict__ Wc1,
    unsigned short* __restrict__ B2P, unsigned short* __restrict__ B3P) {
    int f = blockIdx.x;
    int l = threadIdx.x;
    int g = l >> 4, cc = l & 15;
    if (f < 16) {
        int n = f >> 2, ks = f & 3;
#pragma unroll
        for (int e = 0; e < 8; e++) {
            int row = ks * 32 + 8 * g + e, col = n * 16 + cc;
            B2P[(f * 64 + l) * 8 + e] = f2bf(We2[row * 64 + col]);
        }
    } else {
        int f2 = f - 16;
        int n = f2 >> 1, ks = f2 & 1;
#pragma unroll
        for (int e = 0; e < 8; e++) {
            int row = ks * 32 + 8 * g + e, col = n * 16 + cc;
            B3P[(f2 * 64 + l) * 8 + e] = f2bf(Wc1[row * 64 + col]);
        }
    }
}

// ---- main: one block per (b,i); 4 waves; each wave owns j-tiles jt = w,w+4,...
__global__ __launch_bounds__(256, 2) void egnn_main(
    const float* __restrict__ feats, const float* __restrict__ coors,
    const float* __restrict__ vel, const float* __restrict__ edges,
    const float* __restrict__ We1, const float* __restrict__ be2,
    const float* __restrict__ bc1, const float* __restrict__ Wc2,
    const float* __restrict__ bc2, const float* __restrict__ Wn1,
    const float* __restrict__ bn1, const float* __restrict__ Wn2,
    const float* __restrict__ bn2, const float* __restrict__ Wv,
    const float* __restrict__ bv, const float* __restrict__ HiC,
    const float* __restrict__ HjC, const unsigned short* __restrict__ B2P,
    const unsigned short* __restrict__ B3P, float* __restrict__ out) {
    const int i = blockIdx.x, b = blockIdx.y;
    const int tid = threadIdx.x;
    const int w = tid >> 6, lane = tid & 63;
    const int g = lane >> 4, c = lane & 15;
    const size_t bi = (size_t)b * NN + i;

    // inv vectors (bf16): v0=HiC row, v1=We1 row128 (dist2), v2..5=We1 rows129..132 (edges)
    __shared__ short inv_b16[16][6][8];     // [h/8][vec][elem]
    __shared__ short m3t[4][16][80];        // per-wave transpose buffer (pad 80 for alignment)
    __shared__ float mi_part[4][64];
    __shared__ float agg_part[4][4][3];
    __shared__ float red[128];              // [0:64]=h_i, [64:128]=m_i
    __shared__ float hid[128];
    __shared__ float aggv[3];
    __shared__ float sgate;

    if (tid < 128) {
        int ch = tid >> 3, e = tid & 7;
        inv_b16[ch][0][e] = (short)f2bf(HiC[bi * 128 + tid]);
        inv_b16[ch][1][e] = (short)f2bf(We1[128 * 128 + tid]);
        inv_b16[ch][2][e] = (short)f2bf(We1[129 * 128 + tid]);
        inv_b16[ch][3][e] = (short)f2bf(We1[130 * 128 + tid]);
        inv_b16[ch][4][e] = (short)f2bf(We1[131 * 128 + tid]);
        inv_b16[ch][5][e] = (short)f2bf(We1[132 * 128 + tid]);
    }

    // preload B fragments into registers
    short8 b2f[4][4], b3f[4][2];
#pragma unroll
    for (int n = 0; n < 4; n++)
#pragma unroll
        for (int ks = 0; ks < 4; ks++)
            b2f[n][ks] = *(const short8*)(B2P + ((n * 4 + ks) * 64 + lane) * 8);
#pragma unroll
    for (int n = 0; n < 4; n++)
#pragma unroll
        for (int k2 = 0; k2 < 2; k2++)
            b3f[n][k2] = *(const short8*)(B3P + ((n * 2 + k2) * 64 + lane) * 8);

    float be2r[4], bc1r[4], wc2r[4];
#pragma unroll
    for (int n = 0; n < 4; n++) {
        be2r[n] = be2[n * 16 + c];
        bc1r[n] = bc1[n * 16 + c];
        wc2r[n] = Wc2[n * 16 + c];
    }
    const float bc2v = bc2[0];
    const float ci0 = coors[bi * 3], ci1 = coors[bi * 3 + 1], ci2 = coors[bi * 3 + 2];
    const float cic = (c == 0) ? ci0 : ((c == 1) ? ci1 : ci2);

    float macc[4] = {0.f, 0.f, 0.f, 0.f};
    float aggp = 0.f;
    const f4 zero4 = {0.f, 0.f, 0.f, 0.f};

    __syncthreads();

    for (int jt = w; jt < 24; jt += 4) {
        const int j = jt * 16 + c;
        const f4 ev = *(const f4*)&edges[(((size_t)bi) * NN + j) * 4];
        const float cj0 = coors[((size_t)b * NN + j) * 3];
        const float cj1 = coors[((size_t)b * NN + j) * 3 + 1];
        const float cj2 = coors[((size_t)b * NN + j) * 3 + 2];
        const float r0 = ci0 - cj0, r1 = ci1 - cj1, r2 = ci2 - cj2;
        const float d2 = r0 * r0 + r1 * r1 + r2 * r2;
        const float* hjrow = HjC + ((size_t)b * NN + j) * 128;

        f4 c2[4] = {zero4, zero4, zero4, zero4};
#pragma unroll
        for (int ks = 0; ks < 4; ks++) {
            f4 hA = *(const f4*)(hjrow + ks * 32 + 8 * g);
            f4 hB = *(const f4*)(hjrow + ks * 32 + 8 * g + 4);
            const short8* invp = (const short8*)&inv_b16[ks * 4 + g][0][0];
            short8 vh = invp[0], vwd = invp[1], w0 = invp[2], w1 = invp[3], w2 = invp[4], w3 = invp[5];
            short8 af;
#pragma unroll
            for (int e = 0; e < 8; e++) {
                float hj = (e < 4) ? hA[e] : hB[e - 4];
                float pre = bfu(vh[e]) + hj;
                pre += d2 * bfu(vwd[e]);
                pre += ev.x * bfu(w0[e]);
                pre += ev.y * bfu(w1[e]);
                pre += ev.z * bfu(w2[e]);
                pre += ev.w * bfu(w3[e]);
                af[e] = (short)f2bf(siluf(pre));
            }
#pragma unroll
            for (int n = 0; n < 4; n++)
                c2[n] = __builtin_amdgcn_mfma_f32_16x16x32_bf16(af, b2f[n][ks], c2[n], 0, 0, 0);
        }
        // stage2 epilogue: m = silu(M2 + be2); accumulate m_i; stash transposed for stage3
#pragma unroll
        for (int n = 0; n < 4; n++) {
#pragma unroll
            for (int r = 0; r < 4; r++) {
                float s = siluf(c2[n][r] + be2r[n]);
                macc[n] += s;
                m3t[w][4 * g + r][n * 16 + c] = (short)f2bf(s);
            }
        }
        __syncthreads();
        f4 c3[4] = {zero4, zero4, zero4, zero4};
#pragma unroll
        for (int k2 = 0; k2 < 2; k2++) {
            short8 a3 = *(const short8*)&m3t[w][c][k2 * 32 + 8 * g];
#pragma unroll
            for (int n = 0; n < 4; n++)
                c3[n] = __builtin_amdgcn_mfma_f32_16x16x32_bf16(a3, b3f[n][k2], c3[n], 0, 0, 0);
        }
        __syncthreads();
        // stage3 epilogue: cw = silu(C3 + bc1) @ Wc2 + bc2; agg += rel*cw
        float cwp[4] = {0.f, 0.f, 0.f, 0.f};
#pragma unroll
        for (int n = 0; n < 4; n++) {
#pragma unroll
            for (int r = 0; r < 4; r++) {
                float tt = siluf(c3[n][r] + bc1r[n]);
                cwp[r] += tt * wc2r[n];
            }
        }
#pragma unroll
        for (int r = 0; r < 4; r++) {
            float t = cwp[r];
            t += __shfl_xor(t, 1);
            t += __shfl_xor(t, 2);
            t += __shfl_xor(t, 4);
            t += __shfl_xor(t, 8);
            if (c < 3) {
                int j2 = jt * 16 + 4 * g + r;
                float cjr = coors[((size_t)b * NN + j2) * 3 + c];
                aggp += (cic - cjr) * (t + bc2v);
            }
        }
    }

    // fold per-lane partials
#pragma unroll
    for (int n = 0; n < 4; n++) {
        macc[n] += __shfl_xor(macc[n], 16);
        macc[n] += __shfl_xor(macc[n], 32);
    }
    if (g == 0) {
        mi_part[w][c] = macc[0];
        mi_part[w][16 + c] = macc[1];
        mi_part[w][32 + c] = macc[2];
        mi_part[w][48 + c] = macc[3];
    }
    if (c < 3) agg_part[w][g][c] = aggp;
    __syncthreads();

    // epilogue: node MLP + coordinate/velocity outputs
    if (tid < 64) {
        float mi = mi_part[0][tid] + mi_part[1][tid] + mi_part[2][tid] + mi_part[3][tid];
        red[64 + tid] = mi;
        float hv = feats[bi * 64 + tid];
        red[tid] = hv;
        float gp = hv * Wv[tid];
        gp += __shfl_xor(gp, 1);
        gp += __shfl_xor(gp, 2);
        gp += __shfl_xor(gp, 4);
        gp += __shfl_xor(gp, 8);
        gp += __shfl_xor(gp, 16);
        gp += __shfl_xor(gp, 32);
        if (tid == 0) sgate = gp + bv[0];
    } else if (tid < 67) {
        int cc2 = tid - 64;
        float s = 0.f;
        for (int ww = 0; ww < 4; ww++)
            for (int gg = 0; gg < 4; gg++) s += agg_part[ww][gg][cc2];
        aggv[cc2] = s * (1.f / 384.f);
    }
    __syncthreads();
    if (tid < 128) {
        float acc = bn1[tid];
        for (int k = 0; k < 128; k++) acc += red[k] * Wn1[k * 128 + tid];
        hid[tid] = siluf(acc);
    }
    __syncthreads();
    if (tid < 64) {
        float acc = bn2[tid];
        for (int k = 0; k < 128; k++) acc += hid[k] * Wn2[k * 64 + tid];
        out[bi * 64 + tid] = red[tid] + acc;
    } else if (tid < 67) {
        int cc = tid - 64;
        size_t base = bi * 3 + cc;
        float vn = sgate * vel[base] + aggv[cc];
        float cn = coors[base] + vn;
        out[OUT1OFF + base] = seluf(cn);
        out[OUT2OFF + base] = seluf(vn);
    }
}

extern "C" void kernel_launch(void* const* d_in, const int* in_sizes, int n_in,
                              void* d_out, int out_size, void* d_ws, size_t ws_size,
                              hipStream_t stream) {
    const float* feats = (const float*)d_in[0];
    const float* coors = (const float*)d_in[1];
    const float* vel   = (const float*)d_in[2];
    const float* edges = (const float*)d_in[3];
    const float* We1   = (const float*)d_in[4];
    const float* be1   = (const float*)d_in[5];
    const float* We2   = (const float*)d_in[6];
    const float* be2   = (const float*)d_in[7];
    const float* Wc1   = (const float*)d_in[8];
    const float* bc1   = (const float*)d_in[9];
    const float* Wc2   = (const float*)d_in[10];
    const float* bc2   = (const float*)d_in[11];
    const float* Wn1   = (const float*)d_in[12];
    const float* bn1   = (const float*)d_in[13];
    const float* Wn2   = (const float*)d_in[14];
    const float* bn2   = (const float*)d_in[15];
    const float* Wv    = (const float*)d_in[16];
    const float* bv    = (const float*)d_in[17];

    float* HiC = (float*)d_ws;                       // 393216 f32
    float* HjC = HiC + 393216;                       // 393216 f32
    unsigned short* B2P = (unsigned short*)(HjC + 393216);  // 8192 u16
    unsigned short* B3P = B2P + 8192;                // 4096 u16
    float* out = (float*)d_out;

    egnn_prep1<<<384, 128, 0, stream>>>(feats, We1, be1, HiC, HjC);
    egnn_prep2<<<24, 64, 0, stream>>>(We2, Wc1, B2P, B3P);
    egnn_main<<<dim3(384, 8), 256, 0, stream>>>(feats, coors, vel, edges, We1, be2,
                                                bc1, Wc2, bc2, Wn1, bn1, Wn2, bn2,
                                                Wv, bv, HiC, HjC, B2P, B3P, out);
}

// Round 2
// 127.831 us; speedup vs baseline: 1.6179x; 1.6179x over previous
//
#include <hip/hip_runtime.h>
#include <hip/hip_bf16.h>
#include <cstdint>

#define NN 384
#define OUT1OFF 196608
#define OUT2OFF 205824

typedef float f4 __attribute__((ext_vector_type(4)));
typedef short short8 __attribute__((ext_vector_type(8)));
typedef unsigned int u32;

union FragU { short8 s; u32 w[4]; };

__device__ inline unsigned short f2bf(float f) {
    u32 u = __float_as_uint(f);
    return (unsigned short)((u + 0x7fffu + ((u >> 16) & 1u)) >> 16);
}
__device__ inline u32 pkbf(float lo, float hi) {
    u32 r;
    asm("v_cvt_pk_bf16_f32 %0, %1, %2" : "=v"(r) : "v"(lo), "v"(hi));
    return r;
}
__device__ inline float siluf(float x) {
    return x * __builtin_amdgcn_rcpf(1.0f + __expf(-x));
}
__device__ inline float seluf(float x) {
    const float sc = 1.0507009873554805f, al = 1.6732632423543772f;
    return x > 0.f ? sc * x : sc * al * (__expf(x) - 1.f);
}

#define DSFENCE() do { asm volatile("s_waitcnt lgkmcnt(0)" ::: "memory"); \
                       __builtin_amdgcn_sched_barrier(0); } while (0)

// ---- prep1: HiC[row,h] = be1[h] + feats[row,:]@We1[0:64,h]
//            HjC[row,h] =          feats[row,:]@We1[64:128,h]
__global__ __launch_bounds__(128) void egnn_prep1(
    const float* __restrict__ feats, const float* __restrict__ We1,
    const float* __restrict__ be1, float* __restrict__ HiC, float* __restrict__ HjC) {
    int r0 = blockIdx.x * 8;
    int t = threadIdx.x;
    __shared__ float fr[8][64];
    for (int k = t; k < 512; k += 128) fr[k >> 6][k & 63] = feats[(size_t)r0 * 64 + k];
    __syncthreads();
    float a1[8], a2[8];
#pragma unroll
    for (int r = 0; r < 8; r++) { a1[r] = be1[t]; a2[r] = 0.f; }
    for (int d = 0; d < 64; d++) {
        float w1 = We1[d * 128 + t], w2 = We1[(64 + d) * 128 + t];
#pragma unroll
        for (int r = 0; r < 8; r++) { a1[r] += fr[r][d] * w1; a2[r] += fr[r][d] * w2; }
    }
#pragma unroll
    for (int r = 0; r < 8; r++) {
        HiC[(size_t)(r0 + r) * 128 + t] = a1[r];
        HjC[(size_t)(r0 + r) * 128 + t] = a2[r];
    }
}

// ---- prep2: pack We2^T / Wc1^T as MFMA A-fragments (weights-as-A swapped form)
// A-frag: lane(g,c) elem e of frag (n,ks): A[row=c][k=8g+e+32ks] = W[k][n*16+c]
__global__ __launch_bounds__(64) void egnn_prep2(
    const float* __restrict__ We2, const float* __restrict__ Wc1,
    unsigned short* __restrict__ B2P, unsigned short* __restrict__ B3P) {
    int f = blockIdx.x;
    int l = threadIdx.x;
    int g = l >> 4, cc = l & 15;
    if (f < 16) {
        int n = f >> 2, ks = f & 3;
#pragma unroll
        for (int e = 0; e < 8; e++) {
            int row = ks * 32 + 8 * g + e, col = n * 16 + cc;
            B2P[(f * 64 + l) * 8 + e] = f2bf(We2[row * 64 + col]);
        }
    } else {
        int f2 = f - 16;
        int n = f2 >> 1, k2 = f2 & 1;
#pragma unroll
        for (int e = 0; e < 8; e++) {
            int row = k2 * 32 + 8 * g + e, col = n * 16 + cc;
            B3P[(f2 * 64 + l) * 8 + e] = f2bf(Wc1[row * 64 + col]);
        }
    }
}

// ---- main: ONE WAVE per (b,i); 4 waves/block; no block barriers in main loop
__global__ __launch_bounds__(256, 3) void egnn_main(
    const float* __restrict__ feats, const float* __restrict__ coors,
    const float* __restrict__ vel, const float* __restrict__ edges,
    const float* __restrict__ We1,
    const float* __restrict__ be2, const float* __restrict__ bc1,
    const float* __restrict__ Wc2, const float* __restrict__ bc2,
    const float* __restrict__ Wn1, const float* __restrict__ bn1,
    const float* __restrict__ Wn2, const float* __restrict__ bn2,
    const float* __restrict__ Wv, const float* __restrict__ bv,
    const float* __restrict__ HiC, const float* __restrict__ HjC,
    const unsigned short* __restrict__ B2P, const unsigned short* __restrict__ B3P,
    float* __restrict__ out) {
    __shared__ __align__(16) unsigned short W2L[8192];   // 16 frags (n*4+ks)
    __shared__ __align__(16) unsigned short W3L[4096];   // 8 frags (n*2+k2)
    __shared__ __align__(16) short xch[4][16][136];      // per-wave exchange, padded row
    __shared__ __align__(16) float red[4][128];          // hic during loop; [h_i|m_i] at epilogue
    __shared__ __align__(16) float hid[4][128];

    const int tid = threadIdx.x;
    const int w = tid >> 6, lane = tid & 63;
    const int g = lane >> 4, c = lane & 15;

    // stage weight frags to LDS (once)
    {
        const uint4* s2 = (const uint4*)B2P; uint4* dst2 = (uint4*)W2L;
        for (int k = tid; k < 1024; k += 256) dst2[k] = s2[k];
        const uint4* s3 = (const uint4*)B3P; uint4* dst3 = (uint4*)W3L;
        for (int k = tid; k < 512; k += 256) dst3[k] = s3[k];
    }

    const int flat = blockIdx.x * 4 + w;   // == b*NN + i
    const int b = flat / NN;
    const size_t bi = (size_t)flat;

    // HiC row into per-wave LDS (used as MFMA C-init each tile)
    red[w][lane] = HiC[bi * 128 + lane];
    red[w][64 + lane] = HiC[bi * 128 + 64 + lane];
    __syncthreads();

    // stage-1 A-frags (W5 = We1 rows 128..132), nonzero only on g==0 lanes
    u32 w1p0[8], w1p1[8], w1p2[8];
#pragma unroll
    for (int n = 0; n < 8; n++) {
        float v0 = 0.f, v1 = 0.f, v2 = 0.f, v3 = 0.f, v4 = 0.f;
        if (g == 0) {
            const int h = n * 16 + c;
            v0 = We1[128 * 128 + h]; v1 = We1[129 * 128 + h];
            v2 = We1[130 * 128 + h]; v3 = We1[131 * 128 + h];
            v4 = We1[132 * 128 + h];
        }
        w1p0[n] = pkbf(v0, v1);
        w1p1[n] = pkbf(v2, v3);
        w1p2[n] = pkbf(v4, 0.f);
    }

    f4 be2v[4], bc1v[4], wc2v[4];
#pragma unroll
    for (int n = 0; n < 4; n++) {
        be2v[n] = *(const f4*)&be2[n * 16 + 4 * g];
        bc1v[n] = *(const f4*)&bc1[n * 16 + 4 * g];
        wc2v[n] = *(const f4*)&Wc2[n * 16 + 4 * g];
    }
    const float bc2v = bc2[0];
    const float ci0 = coors[bi * 3], ci1 = coors[bi * 3 + 1], ci2 = coors[bi * 3 + 2];
    const float cig = (g == 0) ? ci0 : ((g == 1) ? ci1 : ci2);

    f4 maccv[4];
#pragma unroll
    for (int n = 0; n < 4; n++) maccv[n] = (f4){0.f, 0.f, 0.f, 0.f};
    float aggp = 0.f;

    short* xrow = &xch[w][c][0];
    const unsigned short* w2base = &W2L[lane * 8];
    const unsigned short* w3base = &W3L[lane * 8];
    const float* redw = &red[w][0];

#pragma unroll 1
    for (int jt = 0; jt < 24; ++jt) {
        const int j = jt * 16 + c;
        const float* cjp = &coors[((size_t)b * NN + j) * 3];
        const float cj0 = cjp[0], cj1 = cjp[1], cj2 = cjp[2];
        const f4 ev = *(const f4*)&edges[(bi * NN + j) * 4];
        const float* hjp = &HjC[((size_t)b * NN + j) * 128];
        f4 hjv[8];
#pragma unroll
        for (int n = 0; n < 8; n++) hjv[n] = *(const f4*)&hjp[n * 16 + 4 * g];
        const float r0 = ci0 - cj0, r1 = ci1 - cj1, r2 = ci2 - cj2;
        const float d2v = r0 * r0 + r1 * r1 + r2 * r2;

        FragU b1;
        b1.w[0] = (g == 0) ? pkbf(d2v, ev.x) : 0u;
        b1.w[1] = (g == 0) ? pkbf(ev.y, ev.z) : 0u;
        b1.w[2] = (g == 0) ? pkbf(ev.w, 0.f) : 0u;
        b1.w[3] = 0u;

        // ---- stage 1: pre = W5·x (MFMA, C=HiC) + HjC ; silu ; pack into xch
#pragma unroll
        for (int n = 0; n < 8; n++) {
            FragU a1;
            a1.w[0] = w1p0[n]; a1.w[1] = w1p1[n]; a1.w[2] = w1p2[n]; a1.w[3] = 0u;
            const f4 hcn = *(const f4*)&redw[n * 16 + 4 * g];
            f4 d1 = __builtin_amdgcn_mfma_f32_16x16x32_bf16(a1.s, b1.s, hcn, 0, 0, 0);
            f4 p = d1 + hjv[n];
            const u32 lo = pkbf(siluf(p.x), siluf(p.y));
            const u32 hi = pkbf(siluf(p.z), siluf(p.w));
            *(uint2*)&xrow[n * 16 + 4 * g] = make_uint2(lo, hi);
        }
        DSFENCE();

        // ---- stage 2: M2 = We2^T · m1^T  (+be2 via C-init)
        f4 c2[4];
#pragma unroll
        for (int n = 0; n < 4; n++) c2[n] = be2v[n];
#pragma unroll
        for (int ks = 0; ks < 4; ks++) {
            const short8 b2 = *(const short8*)&xrow[ks * 32 + 8 * g];
#pragma unroll
            for (int n = 0; n < 4; n++) {
                const short8 wf = *(const short8*)&w2base[(n * 4 + ks) * 512];
                c2[n] = __builtin_amdgcn_mfma_f32_16x16x32_bf16(wf, b2, c2[n], 0, 0, 0);
            }
        }
#pragma unroll
        for (int n = 0; n < 4; n++) {
            f4 s2;
            s2.x = siluf(c2[n].x); s2.y = siluf(c2[n].y);
            s2.z = siluf(c2[n].z); s2.w = siluf(c2[n].w);
            maccv[n] += s2;
            *(uint2*)&xrow[n * 16 + 4 * g] = make_uint2(pkbf(s2.x, s2.y), pkbf(s2.z, s2.w));
        }
        DSFENCE();

        // ---- stage 3: cwh = Wc1^T · m^T (+bc1 via C-init); cw = silu(cwh)·Wc2 + bc2
        f4 c3[4];
#pragma unroll
        for (int n = 0; n < 4; n++) c3[n] = bc1v[n];
#pragma unroll
        for (int k2 = 0; k2 < 2; k2++) {
            const short8 b3 = *(const short8*)&xrow[k2 * 32 + 8 * g];
#pragma unroll
            for (int n = 0; n < 4; n++) {
                const short8 wf = *(const short8*)&w3base[(n * 2 + k2) * 512];
                c3[n] = __builtin_amdgcn_mfma_f32_16x16x32_bf16(wf, b3, c3[n], 0, 0, 0);
            }
        }
        float cwp = 0.f;
#pragma unroll
        for (int n = 0; n < 4; n++) {
            cwp += siluf(c3[n].x) * wc2v[n].x;
            cwp += siluf(c3[n].y) * wc2v[n].y;
            cwp += siluf(c3[n].z) * wc2v[n].z;
            cwp += siluf(c3[n].w) * wc2v[n].w;
        }
        cwp += __shfl_xor(cwp, 16);
        cwp += __shfl_xor(cwp, 32);
        const float cw = cwp + bc2v;
        const float cjg = (g == 0) ? cj0 : ((g == 1) ? cj1 : cj2);
        aggp += (cig - cjg) * cw;   // valid for g<3; g==3 partial is never read
    }

    // ---- per-wave epilogue (no cross-wave traffic)
#pragma unroll
    for (int n = 0; n < 4; n++) {
#pragma unroll
        for (int r = 0; r < 4; r++) {
            float v = maccv[n][r];
            v += __shfl_xor(v, 1); v += __shfl_xor(v, 2);
            v += __shfl_xor(v, 4); v += __shfl_xor(v, 8);
            maccv[n][r] = v;
        }
    }
    const float fv = feats[bi * 64 + lane];
    float gp = fv * Wv[lane];
    gp += __shfl_xor(gp, 1);  gp += __shfl_xor(gp, 2);
    gp += __shfl_xor(gp, 4);  gp += __shfl_xor(gp, 8);
    gp += __shfl_xor(gp, 16); gp += __shfl_xor(gp, 32);
    const float sgate = gp + bv[0];

    float aggr = aggp;
    aggr += __shfl_xor(aggr, 1); aggr += __shfl_xor(aggr, 2);
    aggr += __shfl_xor(aggr, 4); aggr += __shfl_xor(aggr, 8);

    red[w][lane] = fv;
    if (c == 0) {
#pragma unroll
        for (int n = 0; n < 4; n++)
            *(f4*)&red[w][64 + n * 16 + 4 * g] = maccv[n];
    }
    DSFENCE();

    // node MLP: hid = silu([h|m_i]@Wn1+bn1); out = h + hid@Wn2+bn2
    float a0 = bn1[lane], a1 = bn1[64 + lane];
#pragma unroll 4
    for (int k0 = 0; k0 < 128; k0 += 4) {
        const f4 rv = *(const f4*)&redw[k0];
#pragma unroll
        for (int kk = 0; kk < 4; kk++) {
            const float* wr = &Wn1[(size_t)(k0 + kk) * 128];
            a0 += rv[kk] * wr[lane];
            a1 += rv[kk] * wr[64 + lane];
        }
    }
    const float h0 = siluf(a0), h1 = siluf(a1);
    hid[w][lane] = h0;
    hid[w][64 + lane] = h1;
    DSFENCE();
    float o = bn2[lane];
    const float* hidw = &hid[w][0];
#pragma unroll 4
    for (int k0 = 0; k0 < 128; k0 += 4) {
        const f4 hv = *(const f4*)&hidw[k0];
#pragma unroll
        for (int kk = 0; kk < 4; kk++)
            o += hv[kk] * Wn2[(size_t)(k0 + kk) * 64 + lane];
    }
    out[bi * 64 + lane] = fv + o;

    if (c == 0 && g < 3) {
        const size_t base = bi * 3 + g;
        const float vn = sgate * vel[base] + aggr * (1.f / 384.f);
        const float cn = coors[base] + vn;
        out[OUT1OFF + base] = seluf(cn);
        out[OUT2OFF + base] = seluf(vn);
    }
}

extern "C" void kernel_launch(void* const* d_in, const int* in_sizes, int n_in,
                              void* d_out, int out_size, void* d_ws, size_t ws_size,
                              hipStream_t stream) {
    const float* feats = (const float*)d_in[0];
    const float* coors = (const float*)d_in[1];
    const float* vel   = (const float*)d_in[2];
    const float* edges = (const float*)d_in[3];
    const float* We1   = (const float*)d_in[4];
    const float* be1   = (const float*)d_in[5];
    const float* We2   = (const float*)d_in[6];
    const float* be2   = (const float*)d_in[7];
    const float* Wc1   = (const float*)d_in[8];
    const float* bc1   = (const float*)d_in[9];
    const float* Wc2   = (const float*)d_in[10];
    const float* bc2   = (const float*)d_in[11];
    const float* Wn1   = (const float*)d_in[12];
    const float* bn1   = (const float*)d_in[13];
    const float* Wn2   = (const float*)d_in[14];
    const float* bn2   = (const float*)d_in[15];
    const float* Wv    = (const float*)d_in[16];
    const float* bv    = (const float*)d_in[17];

    float* HiC = (float*)d_ws;                              // 393216 f32
    float* HjC = HiC + 393216;                              // 393216 f32
    unsigned short* B2P = (unsigned short*)(HjC + 393216);  // 8192 u16
    unsigned short* B3P = B2P + 8192;                       // 4096 u16
    float* out = (float*)d_out;

    egnn_prep1<<<384, 128, 0, stream>>>(feats, We1, be1, HiC, HjC);
    egnn_prep2<<<24, 64, 0, stream>>>(We2, Wc1, B2P, B3P);
    egnn_main<<<768, 256, 0, stream>>>(feats, coors, vel, edges, We1,
                                       be2, bc1, Wc2, bc2, Wn1, bn1, Wn2, bn2,
                                       Wv, bv, HiC, HjC, B2P, B3P, out);
}